// Round 12
// baseline (44.679 us; speedup 1.0000x reference)
//
#include <hip/hip_runtime.h>

// MPS batched contraction via SITE PAIRING (R9/R11-verified algebra):
// G_P[l][pq][d] = Σ_m A_{2P}[l,p,m] A_{2P+1}[m,q,d],  xx[pq] = x_p * y_q,
// left'' = G_P(xx) left.  32 pairs, K=128 each, 32x32x16 f16 MFMA:
//   A-op (G): row d = lane&31, k = 8*(lane>>5) + e
//   B-op (U): col b = lane&31, same k;  C/D: col = lane&31,
//   row l = (reg&3) + 8*(reg>>2) + 4*(lane>>5)
// G-frag kf = pq*2+lh encodes l = 16*lh + (e&3) + 8*(e>>2) + 4*h =>
//   U_frag(kf) = f16(left[e + 8*lh]) * xx[pq]  -- SAME LANE.
//
// R12 vs R11 (29.2us, MfmaUtil 7.7%, 1 wave/SIMD):
//  1) pair chain split: even kf -> accA (FA0), odd kf -> accB (FA1); two
//     independent 4-deep MFMA chains (critical path ~halved), recombined by
//     FA = cvt(accA+accB) at the next pair (16 f32 adds, fused into cvt).
//  2) x staged through LDS TRANSPOSED [quad][row] via global_load_lds
//     (source-permuted so the linear LDS dest IS the transposed layout);
//     reads are 32 consecutive 16B chunks = conflict-free, h-half broadcast.
//     Frees all x registers; ds_read latency hides under the x-independent
//     add+cvt block at each pair start.
//  3) in-place accumulators (chains restart from zv) -- 64 acc regs, no
//     ping-pong partners. Register total ~170 incl. AGPR-eligible accs.
// LDS: G dbuf 64KB + x dbuf 16KB = 81920 B = exactly 2 blocks/CU.

typedef _Float16 half8 __attribute__((ext_vector_type(8)));
typedef float floatx16 __attribute__((ext_vector_type(16)));
typedef float f32x4 __attribute__((ext_vector_type(4)));

#define NPAIRS 32
#define GCHUNK 16384   // halfs per G chunk: 4 pairs * 8 frags * 64 lanes * 8
#define XCHUNK 2048    // floats per x chunk: 4 quads * 128 rows * 4

// ---------------- prep: pair products + fragment packing (R11-proven) -----
__global__ void mps_prep_pair(const float* __restrict__ A, _Float16* __restrict__ Gf) {
    __shared__ float sA0[2048], sA1[2048], sG[4096];
    const int P = blockIdx.x, tid = threadIdx.x;      // 256 threads
    const float* a0p = A + (size_t)(2 * P) * 2048;
    const float* a1p = A + (size_t)(2 * P + 1) * 2048;
#pragma unroll
    for (int i = 0; i < 8; ++i) {
        sA0[tid + 256 * i] = a0p[tid + 256 * i];
        sA1[tid + 256 * i] = a1p[tid + 256 * i];
    }
    __syncthreads();
    {   // thread -> (l, pq, d-half): 16 outputs, dot over m=32 in f32
        const int l = tid >> 3, pq = (tid >> 1) & 3, dh16 = (tid & 1) * 16;
        const int p = pq >> 1, q = pq & 1;
        float accv[16];
#pragma unroll
        for (int dd = 0; dd < 16; ++dd) accv[dd] = 0.f;
        for (int m = 0; m < 32; ++m) {
            const float av = sA0[l * 64 + p * 32 + m];
            const float* bp = &sA1[m * 64 + q * 32 + dh16];
#pragma unroll
            for (int dd = 0; dd < 16; ++dd) accv[dd] += av * bp[dd];
        }
#pragma unroll
        for (int dd = 0; dd < 16; ++dd) sG[l * 128 + pq * 32 + dh16 + dd] = accv[dd];
    }
    __syncthreads();
    const int lane = tid & 63;
    const int h    = lane >> 5;
    const int d    = lane & 31;
#pragma unroll
    for (int pass = 0; pass < 2; ++pass) {
        const int kf = (tid >> 6) + pass * 4;         // 0..7
        const int pq = kf >> 1, lh = kf & 1;
        half8 v;
#pragma unroll
        for (int e = 0; e < 8; ++e) {
            const int l = 16 * lh + (e & 3) + 8 * (e >> 2) + 4 * h;
            v[e] = (_Float16)sG[l * 128 + pq * 32 + d];
        }
        reinterpret_cast<half8*>(Gf)[((size_t)P * 8 + kf) * 64 + lane] = v;
    }
}

// ---------------- main kernel ----------------
#define MF32(A_, B_, C_) __builtin_amdgcn_mfma_f32_32x32x16_f16(A_, B_, C_, 0, 0, 0)

// One pair, one 32-row tile, split chains in-place:
//   FA = cvt(AA + AB); AA = Σ even-kf MFMA (4-deep); AB = Σ odd-kf (4-deep).
#define PAIRT(G, AA, AB, XQ)                                                  \
    {                                                                         \
        half8 FA0_, FA1_;                                                     \
        _Pragma("unroll")                                                     \
        for (int i_ = 0; i_ < 8; ++i_) {                                      \
            FA0_[i_] = (_Float16)(AA[i_] + AB[i_]);                           \
            FA1_[i_] = (_Float16)(AA[8 + i_] + AB[8 + i_]);                   \
        }                                                                     \
        const _Float16 w0_ = (_Float16)(XQ[0] * XQ[2]);                       \
        const _Float16 w1_ = (_Float16)(XQ[0] * XQ[3]);                       \
        const _Float16 w2_ = (_Float16)(XQ[1] * XQ[2]);                       \
        const _Float16 w3_ = (_Float16)(XQ[1] * XQ[3]);                       \
        half8 W0_, W1_, W2_, W3_;                                             \
        _Pragma("unroll")                                                     \
        for (int i_ = 0; i_ < 8; ++i_) {                                      \
            W0_[i_] = w0_; W1_[i_] = w1_; W2_[i_] = w2_; W3_[i_] = w3_;       \
        }                                                                     \
        AA = MF32(G[0], FA0_ * W0_, zv);                                      \
        AB = MF32(G[1], FA1_ * W0_, zv);                                      \
        AA = MF32(G[2], FA0_ * W1_, AA);                                      \
        AB = MF32(G[3], FA1_ * W1_, AB);                                      \
        AA = MF32(G[4], FA0_ * W2_, AA);                                      \
        AB = MF32(G[5], FA1_ * W2_, AB);                                      \
        AA = MF32(G[6], FA0_ * W3_, AA);                                      \
        AB = MF32(G[7], FA1_ * W3_, AB);                                      \
    }

// Read pair PL (local to G buffer BUF) 8 frags into register slot DST.
#define RD(DST, BUF, PL)                                                      \
    {                                                                         \
        _Pragma("unroll")                                                     \
        for (int f_ = 0; f_ < 8; ++f_)                                        \
            DST[f_] = *(const half8*)&smG[(BUF) * GCHUNK                      \
                                          + (((PL) * 8 + f_) * 64 + lane) * 8]; \
    }

// x quad for local pair PP, tile T (conflict-free: consecutive cols ->
// consecutive 16B chunks; lanes 32..63 broadcast with lanes 0..31).
#define XRD(BUF, PP, T)                                                       \
    (*(const f32x4*)&smX[(BUF) * XCHUNK + (PP) * 512 + (wid * 64 + 32 * (T) + col) * 4])

// Stage G chunk C (4 pairs, 32 recs of 1KB) into buffer BUF. 2 waves x 16.
#define STAGEG(C, BUF)                                                        \
    {                                                                         \
        _Pragma("unroll")                                                     \
        for (int r_ = 0; r_ < 16; ++r_) {                                     \
            const int rec_ = r_ * 2 + wid;                                    \
            const _Float16* g_ = Gf + (size_t)(C) * GCHUNK + rec_ * 512 + lane * 8; \
            __builtin_amdgcn_global_load_lds(                                 \
                (const __attribute__((address_space(1))) void*)g_,            \
                (__attribute__((address_space(3))) void*)&smG[(BUF) * GCHUNK + rec_ * 512], \
                16, 0, 0);                                                    \
        }                                                                     \
    }

// Stage x chunk C transposed [quad][row]: record rec covers quad rec>>1,
// rows (rec&1)*64 + lane. Linear LDS dest == transposed layout by
// construction. 2 waves x 4 recs.
#define STAGEX(C, BUF)                                                        \
    {                                                                         \
        _Pragma("unroll")                                                     \
        for (int r_ = 0; r_ < 4; ++r_) {                                      \
            const int rec_  = r_ * 2 + wid;                                   \
            const int quad_ = rec_ >> 1, rowg_ = rec_ & 1;                    \
            const float* s_ = x + (size_t)(brow + rowg_ * 64 + lane) * 128    \
                                + 16 * (C) + 4 * quad_;                       \
            __builtin_amdgcn_global_load_lds(                                 \
                (const __attribute__((address_space(1))) void*)s_,            \
                (__attribute__((address_space(3))) void*)&smX[(BUF) * XCHUNK + rec_ * 256], \
                16, 0, 0);                                                    \
        }                                                                     \
    }

// One 4-pair chunk reading G buffer BUF / x buffer BUF.
#define CHUNKB(C, BUF)                                                        \
    {                                                                         \
        if ((C) < 7) { STAGEG((C) + 1, 1 - (BUF)); STAGEX((C) + 1, 1 - (BUF)); } \
        RD(GB, BUF, 1)                                                        \
        {                                                                     \
            f32x4 xq0_ = XRD(BUF, 0, 0), xq1_ = XRD(BUF, 0, 1);               \
            PAIRT(GA, aA0, aB0, xq0_) PAIRT(GA, aA1, aB1, xq1_)               \
        }                                                                     \
        RD(GA, BUF, 2)                                                        \
        {                                                                     \
            f32x4 xq0_ = XRD(BUF, 1, 0), xq1_ = XRD(BUF, 1, 1);               \
            PAIRT(GB, aA0, aB0, xq0_) PAIRT(GB, aA1, aB1, xq1_)               \
        }                                                                     \
        RD(GB, BUF, 3)                                                        \
        {                                                                     \
            f32x4 xq0_ = XRD(BUF, 2, 0), xq1_ = XRD(BUF, 2, 1);               \
            PAIRT(GA, aA0, aB0, xq0_) PAIRT(GA, aA1, aB1, xq1_)               \
        }                                                                     \
        {                                                                     \
            f32x4 xq0_ = XRD(BUF, 3, 0), xq1_ = XRD(BUF, 3, 1);               \
            PAIRT(GB, aA0, aB0, xq0_) PAIRT(GB, aA1, aB1, xq1_)               \
        }                                                                     \
        __syncthreads();                                                      \
        if ((C) < 7) RD(GA, 1 - (BUF), 0)                                     \
    }

__global__ __launch_bounds__(128, 1) void mps_main(const float* __restrict__ x,
                                                   const _Float16* __restrict__ Gf,
                                                   float* __restrict__ out) {
    __shared__ __align__(16) _Float16 smG[2 * GCHUNK];   // 64 KB
    __shared__ __align__(16) float    smX[2 * XCHUNK];   // 16 KB

    const int lane = threadIdx.x & 63;
    const int wid  = threadIdx.x >> 6;               // 0..1
    const int brow = blockIdx.x * 128;               // block's first batch row
    const int col  = lane & 31;

    floatx16 zv;
#pragma unroll
    for (int i = 0; i < 16; ++i) zv[i] = 0.f;

    // split accs per tile: left = aA + aB; l = (reg&3) + 8*(reg>>2) + 4*h
    floatx16 aA0, aB0, aA1, aB1;
#pragma unroll
    for (int i = 0; i < 16; ++i) { aA0[i] = 0.f; aB0[i] = 0.f; aA1[i] = 0.f; aB1[i] = 0.f; }
    if (lane < 32) { aA0[0] = 1.f; aA1[0] = 1.f; }   // left0 = e0

    half8 GA[8], GB[8];

    STAGEG(0, 0);
    STAGEX(0, 0);
    __syncthreads();
    RD(GA, 0, 0)

    CHUNKB(0, 0)
    CHUNKB(1, 1)
    CHUNKB(2, 0)
    CHUNKB(3, 1)
    CHUNKB(4, 0)
    CHUNKB(5, 1)
    CHUNKB(6, 0)
    CHUNKB(7, 1)

    // out[b] = (aA+aB)[l=0]: reg 0, h=0 -> lanes 0..31
    if (lane < 32) {
        out[brow + wid * 64 + lane]      = aA0[0] + aB0[0];
        out[brow + wid * 64 + 32 + lane] = aA1[0] + aB1[0];
    }
}

extern "C" void kernel_launch(void* const* d_in, const int* in_sizes, int n_in,
                              void* d_out, int out_size, void* d_ws, size_t ws_size,
                              hipStream_t stream) {
    const float* x = (const float*)d_in[0];   // [65536][64][2] f32
    const float* A = (const float*)d_in[1];   // [64][32][2][32] f32
    float* outp = (float*)d_out;              // [65536] f32
    _Float16* Gf = (_Float16*)d_ws;           // 256 KB pair-fragment fp16

    hipLaunchKernelGGL(mps_prep_pair, dim3(NPAIRS), dim3(256), 0, stream, A, Gf);
    hipLaunchKernelGGL(mps_main, dim3(65536 / 128), dim3(128), 0, stream, x, Gf, outp);
}

// Round 13
// 28.766 us; speedup vs baseline: 1.5532x; 1.5532x over previous
//
#include <hip/hip_runtime.h>

// MPS batched contraction via SITE PAIRING (R9/R11-verified algebra):
// G_P[l][pq][d] = Σ_m A_{2P}[l,p,m] A_{2P+1}[m,q,d],  xx[pq] = x_p * y_q,
// left'' = G_P(xx) left.  32 pairs, K=128 each, 32x32x16 f16 MFMA:
//   A-op (G): row d = lane&31, k = 8*(lane>>5) + e
//   B-op (U): col b = lane&31, same k;  C/D: col = lane&31,
//   row l = (reg&3) + 8*(reg>>2) + 4*(lane>>5)
// G-frag kf = pq*2+lh encodes l = 16*lh + (e&3) + 8*(e>>2) + 4*h =>
//   U_frag(kf) = f16(left[e + 8*lh]) * xx[pq]  -- SAME LANE.
//
// R13: kill the structure-invariant cost. R6/R9/R11 all ~30us despite 8x
// LDS-traffic and 4x occupancy differences; the one constant was per-lane
// x loads hitting 32 distinct cache lines per instruction (512B inter-lane
// stride) -> serialized LSU address processing every round. Fix: each block
// loads its whole 128-row x slab ONCE with coalesced f32x4 reads (flat
// index), converts to f16, stores transposed [quad][row] in LDS (stride
// 129 pad -> free 2-way). Per pair: one ds_read_b64, no global x.
// Config: 2048 waves / 8 per CU / 2 per SIMD (R9's proven occupancy),
// 1x32-row tile per wave, JIT G ds_reads (no register pipeline for the
// compiler to sabotage), 2-pair G chunks double-buffered.
// LDS: G 2x16KB + x 33KB = 66KB -> 2 blocks/CU.

typedef _Float16 half8 __attribute__((ext_vector_type(8)));
typedef _Float16 half4 __attribute__((ext_vector_type(4)));
typedef float floatx16 __attribute__((ext_vector_type(16)));
typedef float f32x4 __attribute__((ext_vector_type(4)));

#define NPAIRS 32
#define GCH 8192        // halfs per 2-pair G chunk = 16 KB
#define XSTRIDE 129     // padded half4 units per quad line (bank spread)

// ---------------- prep: pair products + fragment packing (R11-proven) -----
__global__ void mps_prep_pair(const float* __restrict__ A, _Float16* __restrict__ Gf) {
    __shared__ float sA0[2048], sA1[2048], sG[4096];
    const int P = blockIdx.x, tid = threadIdx.x;      // 256 threads
    const float* a0p = A + (size_t)(2 * P) * 2048;
    const float* a1p = A + (size_t)(2 * P + 1) * 2048;
#pragma unroll
    for (int i = 0; i < 8; ++i) {
        sA0[tid + 256 * i] = a0p[tid + 256 * i];
        sA1[tid + 256 * i] = a1p[tid + 256 * i];
    }
    __syncthreads();
    {   // thread -> (l, pq, d-half): 16 outputs, dot over m=32 in f32
        const int l = tid >> 3, pq = (tid >> 1) & 3, dh16 = (tid & 1) * 16;
        const int p = pq >> 1, q = pq & 1;
        float accv[16];
#pragma unroll
        for (int dd = 0; dd < 16; ++dd) accv[dd] = 0.f;
        for (int m = 0; m < 32; ++m) {
            const float av = sA0[l * 64 + p * 32 + m];
            const float* bp = &sA1[m * 64 + q * 32 + dh16];
#pragma unroll
            for (int dd = 0; dd < 16; ++dd) accv[dd] += av * bp[dd];
        }
#pragma unroll
        for (int dd = 0; dd < 16; ++dd) sG[l * 128 + pq * 32 + dh16 + dd] = accv[dd];
    }
    __syncthreads();
    const int lane = tid & 63;
    const int h    = lane >> 5;
    const int d    = lane & 31;
#pragma unroll
    for (int pass = 0; pass < 2; ++pass) {
        const int kf = (tid >> 6) + pass * 4;         // 0..7
        const int pq = kf >> 1, lh = kf & 1;
        half8 v;
#pragma unroll
        for (int e = 0; e < 8; ++e) {
            const int l = 16 * lh + (e & 3) + 8 * (e >> 2) + 4 * h;
            v[e] = (_Float16)sG[l * 128 + pq * 32 + d];
        }
        reinterpret_cast<half8*>(Gf)[((size_t)P * 8 + kf) * 64 + lane] = v;
    }
}

// ---------------- main kernel ----------------
#define MF32(A_, B_, C_) __builtin_amdgcn_mfma_f32_32x32x16_f16(A_, B_, C_, 0, 0, 0)

// Stage 2-pair G chunk C into buffer BUF: 16 recs of 1KB, 4 waves x 4 recs.
#define STAGEG(C, BUF)                                                        \
    {                                                                         \
        _Pragma("unroll")                                                     \
        for (int r_ = 0; r_ < 4; ++r_) {                                      \
            const int rec_ = r_ * 4 + wid;                                    \
            const _Float16* g_ = Gf + (size_t)(C) * GCH + rec_ * 512 + lane * 8; \
            __builtin_amdgcn_global_load_lds(                                 \
                (const __attribute__((address_space(1))) void*)g_,            \
                (__attribute__((address_space(3))) void*)&smG[(BUF) * GCH + rec_ * 512], \
                16, 0, 0);                                                    \
        }                                                                     \
    }

// One pair: x quad from LDS (b64, lanes 32-63 broadcast), 8 JIT G ds_reads,
// FA cvt from acc, 8-MFMA in-place chain. P = global pair, LP = pair-in-chunk.
#define PAIRDO(BUF, LP, P)                                                    \
    {                                                                         \
        const half4 xq_ = smX[(P) * XSTRIDE + r];                             \
        const _Float16 w00_ = xq_[0] * xq_[2];                                \
        const _Float16 w01_ = xq_[0] * xq_[3];                                \
        const _Float16 w10_ = xq_[1] * xq_[2];                                \
        const _Float16 w11_ = xq_[1] * xq_[3];                                \
        half8 G_[8];                                                          \
        _Pragma("unroll")                                                     \
        for (int f_ = 0; f_ < 8; ++f_)                                        \
            G_[f_] = *(const half8*)&smG[(BUF) * GCH + (((LP) * 8 + f_) * 64 + lane) * 8]; \
        half8 FA0_, FA1_;                                                     \
        _Pragma("unroll")                                                     \
        for (int i_ = 0; i_ < 8; ++i_) {                                      \
            FA0_[i_] = (_Float16)acc[i_];                                     \
            FA1_[i_] = (_Float16)acc[8 + i_];                                 \
        }                                                                     \
        floatx16 t_;                                                          \
        t_ = MF32(G_[0], FA0_ * w00_, zv);                                    \
        t_ = MF32(G_[1], FA1_ * w00_, t_);                                    \
        t_ = MF32(G_[2], FA0_ * w01_, t_);                                    \
        t_ = MF32(G_[3], FA1_ * w01_, t_);                                    \
        t_ = MF32(G_[4], FA0_ * w10_, t_);                                    \
        t_ = MF32(G_[5], FA1_ * w10_, t_);                                    \
        t_ = MF32(G_[6], FA0_ * w11_, t_);                                    \
        t_ = MF32(G_[7], FA1_ * w11_, t_);                                    \
        acc = t_;                                                             \
    }

// One 2-pair chunk: stage next chunk up front, compute both pairs, barrier.
#define CHUNK(C, BUF)                                                         \
    {                                                                         \
        if ((C) < 15) STAGEG((C) + 1, 1 - (BUF));                             \
        PAIRDO(BUF, 0, 2 * (C))                                               \
        PAIRDO(BUF, 1, 2 * (C) + 1)                                           \
        __syncthreads();                                                      \
    }

__global__ __launch_bounds__(256, 2) void mps_main(const float* __restrict__ x,
                                                   const _Float16* __restrict__ Gf,
                                                   float* __restrict__ out) {
    __shared__ __align__(16) _Float16 smG[2 * GCH];       // 32 KB
    __shared__ __align__(8)  half4    smX[32 * XSTRIDE];  // 33 KB, [quad][row]

    const int tid  = threadIdx.x;
    const int lane = tid & 63;
    const int wid  = tid >> 6;                 // 0..3
    const int brow = blockIdx.x * 128;         // block's first batch row
    const int col  = lane & 31;
    const int r    = wid * 32 + col;           // this wave's row within block

    STAGEG(0, 0);

    // x -> LDS f16 transposed [quad][row]: coalesced f32x4 global reads
    // (flat quad index j: lane-consecutive addresses), free-2-way ds_writes.
#pragma unroll
    for (int i = 0; i < 16; ++i) {
        const int j   = i * 256 + tid;         // 0..4095
        const int row = j >> 5, q = j & 31;
        const f32x4 v = *(const f32x4*)(x + (size_t)(brow + row) * 128 + 4 * q);
        half4 hv;
        hv[0] = (_Float16)v[0]; hv[1] = (_Float16)v[1];
        hv[2] = (_Float16)v[2]; hv[3] = (_Float16)v[3];
        smX[q * XSTRIDE + row] = hv;
    }

    floatx16 zv;
#pragma unroll
    for (int i = 0; i < 16; ++i) zv[i] = 0.f;

    // acc = left[l], l = (reg&3) + 8*(reg>>2) + 4*(lane>>5)
    floatx16 acc;
#pragma unroll
    for (int i = 0; i < 16; ++i) acc[i] = 0.f;
    if (lane < 32) acc[0] = 1.f;               // left0 = e0

    __syncthreads();                            // x in LDS + G chunk 0 ready

    CHUNK(0, 0)   CHUNK(1, 1)   CHUNK(2, 0)   CHUNK(3, 1)
    CHUNK(4, 0)   CHUNK(5, 1)   CHUNK(6, 0)   CHUNK(7, 1)
    CHUNK(8, 0)   CHUNK(9, 1)   CHUNK(10, 0)  CHUNK(11, 1)
    CHUNK(12, 0)  CHUNK(13, 1)  CHUNK(14, 0)  CHUNK(15, 1)

    // out[b] = left_final[l=0]: reg 0, h=0 -> lanes 0..31
    if (lane < 32) out[brow + wid * 32 + lane] = acc[0];
}

extern "C" void kernel_launch(void* const* d_in, const int* in_sizes, int n_in,
                              void* d_out, int out_size, void* d_ws, size_t ws_size,
                              hipStream_t stream) {
    const float* x = (const float*)d_in[0];   // [65536][64][2] f32
    const float* A = (const float*)d_in[1];   // [64][32][2][32] f32
    float* outp = (float*)d_out;              // [65536] f32
    _Float16* Gf = (_Float16*)d_ws;           // 256 KB pair-fragment fp16

    hipLaunchKernelGGL(mps_prep_pair, dim3(NPAIRS), dim3(256), 0, stream, A, Gf);
    hipLaunchKernelGGL(mps_main, dim3(65536 / 128), dim3(256), 0, stream, x, Gf, outp);
}